// Round 8
// baseline (91.617 us; speedup 1.0000x reference)
//
#include <hip/hip_runtime.h>

// QuantizedLinear: out[t][o] = sum_k x[t][k] * (w_q[o][k]-128)*scale[o] + bias[o]
// M=16, N=8192, K=8192. Memory-bound on w_q (256 MB int32, read once).
//
// R7 structure: split-K + stage-x-once. R6 (75.7us, 3.5 TB/s) was limited by
// x-loads sharing the vmcnt counter with the w-stream: in-order vmcnt waits
// serialized 16 L2 round-trips per k-step. Here each block owns a K-slice of
// 1024: x-slice (64 KB) staged to LDS with ONE barrier, then a barrier-free
// w-stream (vmcnt = w only, depth-2 software pipeline) with x via lgkmcnt.
// Partials go to d_ws (4 MB) + a reduce kernel (deterministic); atomicAdd
// fallback if ws_size is too small.
// (Resubmitted unchanged after round-7 infra failure.)

#define IN_F   8192
#define OUT_F  8192
#define NT     16
#define BLOCK  512
#define WAVES  (BLOCK / 64)          // 8
#define W_O    4
#define CH_PER_BLOCK (WAVES * W_O)   // 32
#define K_SLICE 1024
#define N_SLICE (IN_F / K_SLICE)     // 8
#define KSTEPS  (K_SLICE / 256)      // 4

template <bool ATOMIC>
__global__ __launch_bounds__(BLOCK, 4)
void qlin_main(const float* __restrict__ x,      // [16][8192]
               const int*   __restrict__ w_q,    // [8192][8192]
               const float* __restrict__ scale,  // [8192]
               float*       __restrict__ dst)    // ws [8][16][8192] or out
{
    __shared__ float xs[NT][K_SLICE];            // 64 KB

    const int tid   = threadIdx.x;
    const int lane  = tid & 63;
    const int wave  = tid >> 6;
    const int slice = blockIdx.y;
    const int k0    = slice * K_SLICE;
    const int o_base = blockIdx.x * CH_PER_BLOCK + wave * W_O;

    // ---- stage x slice ONCE (only barrier in the kernel) ----
#pragma unroll
    for (int r = 0; r < (NT * K_SLICE) / (BLOCK * 4); ++r) {   // 8
        const int flat = r * (BLOCK * 4) + tid * 4;
        const int i = flat >> 10;                 // / K_SLICE
        const int k = flat & (K_SLICE - 1);
        *reinterpret_cast<float4*>(&xs[i][k]) =
            *reinterpret_cast<const float4*>(&x[(size_t)i * IN_F + k0 + k]);
    }
    __syncthreads();

    // ---- barrier-free w-stream: 4 k-steps, depth-2 pipeline ----
    const int* __restrict__ wp0 = w_q + (size_t)(o_base + 0) * IN_F + k0 + lane * 4;
    const int* __restrict__ wp1 = w_q + (size_t)(o_base + 1) * IN_F + k0 + lane * 4;
    const int* __restrict__ wp2 = w_q + (size_t)(o_base + 2) * IN_F + k0 + lane * 4;
    const int* __restrict__ wp3 = w_q + (size_t)(o_base + 3) * IN_F + k0 + lane * 4;

    float acc[NT][W_O];
#pragma unroll
    for (int t = 0; t < NT; ++t)
#pragma unroll
        for (int j = 0; j < W_O; ++j) acc[t][j] = 0.0f;

    int4 wa[W_O], wb[W_O];

#define LOADW(buf, ofs)                                              \
    buf[0] = *reinterpret_cast<const int4*>(wp0 + (ofs));            \
    buf[1] = *reinterpret_cast<const int4*>(wp1 + (ofs));            \
    buf[2] = *reinterpret_cast<const int4*>(wp2 + (ofs));            \
    buf[3] = *reinterpret_cast<const int4*>(wp3 + (ofs));

#define STEP(buf, ks)                                                \
    {                                                                \
        const int kl = (ks) * 256 + lane * 4;                        \
        float wf[W_O][4];                                            \
        _Pragma("unroll")                                            \
        for (int j = 0; j < W_O; ++j) {                              \
            wf[j][0] = (float)(buf[j].x - 128);                      \
            wf[j][1] = (float)(buf[j].y - 128);                      \
            wf[j][2] = (float)(buf[j].z - 128);                      \
            wf[j][3] = (float)(buf[j].w - 128);                      \
        }                                                            \
        _Pragma("unroll")                                            \
        for (int t = 0; t < NT; ++t) {                               \
            const float4 xv = *reinterpret_cast<const float4*>(&xs[t][kl]); \
            _Pragma("unroll")                                        \
            for (int j = 0; j < W_O; ++j) {                          \
                acc[t][j] += wf[j][0] * xv.x;                        \
                acc[t][j] += wf[j][1] * xv.y;                        \
                acc[t][j] += wf[j][2] * xv.z;                        \
                acc[t][j] += wf[j][3] * xv.w;                        \
            }                                                        \
        }                                                            \
    }

    LOADW(wa, 0)            // ks=0
    LOADW(wb, 256)          // ks=1
    STEP(wa, 0)
    LOADW(wa, 512)          // ks=2
    STEP(wb, 1)
    LOADW(wb, 768)          // ks=3
    STEP(wa, 2)
    STEP(wb, 3)

#undef LOADW
#undef STEP

    // ---- cross-lane reduction: 64 (t,j) values, 6-step butterfly ----
    float myval = 0.0f;
#pragma unroll
    for (int t = 0; t < NT; ++t) {
#pragma unroll
        for (int j = 0; j < W_O; ++j) {
            float v = acc[t][j];
#pragma unroll
            for (int off = 32; off > 0; off >>= 1)
                v += __shfl_xor(v, off, 64);
            if (lane == (t * W_O + j)) myval = v;
        }
    }

    const int t_o = lane >> 2;
    const int o   = o_base + (lane & 3);
    if (ATOMIC) {
        atomicAdd(&dst[(size_t)t_o * OUT_F + o], myval * scale[o]);
    } else {
        dst[((size_t)(slice * NT + t_o)) * OUT_F + o] = myval;
    }
}

__global__ __launch_bounds__(512)
void qlin_reduce(const float* __restrict__ ws, const float* __restrict__ scale,
                 const float* __restrict__ bias, float* __restrict__ out)
{
    const int idx = blockIdx.x * 512 + threadIdx.x;   // 0 .. 16*8192-1
    const int o = idx & (OUT_F - 1);
    const int t = idx >> 13;
    float s = 0.0f;
#pragma unroll
    for (int sl = 0; sl < N_SLICE; ++sl)
        s += ws[((size_t)(sl * NT + t)) * OUT_F + o];
    out[idx] = s * scale[o] + bias[o];
}

__global__ __launch_bounds__(512)
void qlin_init(const float* __restrict__ bias, float* __restrict__ out)
{
    const int idx = blockIdx.x * 512 + threadIdx.x;
    out[idx] = bias[idx & (OUT_F - 1)];
}

extern "C" void kernel_launch(void* const* d_in, const int* in_sizes, int n_in,
                              void* d_out, int out_size, void* d_ws, size_t ws_size,
                              hipStream_t stream) {
    const float* x     = (const float*)d_in[0];
    const int*   w_q   = (const int*)d_in[1];
    const float* scale = (const float*)d_in[2];
    const float* bias  = (const float*)d_in[3];
    float*       out   = (float*)d_out;

    const dim3 grid(OUT_F / CH_PER_BLOCK, N_SLICE);   // 256 x 8
    const dim3 block(BLOCK);
    const size_t ws_need = (size_t)N_SLICE * NT * OUT_F * sizeof(float);  // 4 MB

    if (ws_size >= ws_need) {
        float* ws = (float*)d_ws;
        qlin_main<false><<<grid, block, 0, stream>>>(x, w_q, scale, ws);
        qlin_reduce<<<(NT * OUT_F) / 512, 512, 0, stream>>>(ws, scale, bias, out);
    } else {
        qlin_init<<<(NT * OUT_F) / 512, 512, 0, stream>>>(bias, out);
        qlin_main<true><<<grid, block, 0, stream>>>(x, w_q, scale, out);
    }
}